// Round 1
// baseline (109.048 us; speedup 1.0000x reference)
//
#include <hip/hip_runtime.h>

// Joint bilateral filter block.
// Shapes: x (1,1,20,96,96) f32; guide_im (N,1,7,7,7) f32, N = 16*96*96 = 147456;
// domain_neighbor (1,1,7,7,7); four 3x3x3 conv weights + scalar biases.
// out (1,1,16,96,96) f32.
//
// Patch n corresponds to output voxel n with n = dd*9216 + h*96 + w,
// dd in [0,16), using x depths dd+1..dd+3 and H/W window with zero pad.

#define NPATCH 147456

// ---------------- Kernel A: domain branch (runs once, 1 block) --------------
__global__ __launch_bounds__(128) void domain_branch_kernel(
    const float* __restrict__ dn,
    const float* __restrict__ w1, const float* __restrict__ b1,
    const float* __restrict__ w2, const float* __restrict__ b2,
    float* __restrict__ dom_out)
{
    __shared__ float s_in[344];
    __shared__ float s_c1[128];
    const int t = threadIdx.x;
    for (int idx = t; idx < 343; idx += 128) s_in[idx] = dn[idx];
    __syncthreads();
    if (t < 125) {
        const int i = t / 25, j = (t / 5) % 5, k = t % 5;
        float acc = b1[0];
        const float* base = &s_in[i * 49 + j * 7 + k];
#pragma unroll
        for (int dz = 0; dz < 3; ++dz)
#pragma unroll
            for (int dy = 0; dy < 3; ++dy)
#pragma unroll
                for (int dx = 0; dx < 3; ++dx)
                    acc = fmaf(base[dz * 49 + dy * 7 + dx], w1[dz * 9 + dy * 3 + dx], acc);
        s_c1[t] = fmaxf(acc, 0.f);
    }
    __syncthreads();
    if (t < 27) {
        const int dz = t / 9, dy = (t / 3) % 3, dx = t % 3;
        float acc = b2[0];
#pragma unroll
        for (int u = 0; u < 3; ++u)
#pragma unroll
            for (int v = 0; v < 3; ++v)
#pragma unroll
                for (int q = 0; q < 3; ++q)
                    acc = fmaf(s_c1[(dz + u) * 25 + (dy + v) * 5 + (dx + q)],
                               w2[u * 9 + v * 3 + q], acc);
        dom_out[t] = fmaxf(acc, 0.f);
    }
}

// ---------------- Kernel B: range branch + bilateral combine ----------------
// Block = 256 threads = 2 groups of 128; each group owns one patch.
__global__ __launch_bounds__(256) void jbf_main_kernel(
    const float* __restrict__ guide, const float* __restrict__ x,
    const float* __restrict__ w1, const float* __restrict__ b1,
    const float* __restrict__ w2, const float* __restrict__ b2,
    const float* __restrict__ dom, float* __restrict__ out)
{
    __shared__ float s_in[2][344];
    __shared__ float s_c1[2][128];

    const int tid = threadIdx.x;
    const int grp = tid >> 7;       // 0 or 1
    const int lt  = tid & 127;      // lane within group
    const int n   = blockIdx.x * 2 + grp;

    // ---- stage patch (contiguous 343 floats -> fully coalesced) ----
    const float* gp = guide + (long long)n * 343;
    for (int idx = lt; idx < 343; idx += 128) s_in[grp][idx] = gp[idx];
    __syncthreads();

    // ---- conv1 (7^3 -> 5^3), one output per thread ----
    if (lt < 125) {
        const int i = lt / 25, j = (lt / 5) % 5, k = lt % 5;
        float acc = b1[0];
        const float* base = &s_in[grp][i * 49 + j * 7 + k];
#pragma unroll
        for (int dz = 0; dz < 3; ++dz)
#pragma unroll
            for (int dy = 0; dy < 3; ++dy)
#pragma unroll
                for (int dx = 0; dx < 3; ++dx)
                    acc = fmaf(base[dz * 49 + dy * 7 + dx], w1[dz * 9 + dy * 3 + dx], acc);
        s_c1[grp][lt] = fmaxf(acc, 0.f);
    }
    __syncthreads();

    // ---- conv2 (5^3 -> 3^3) + weights + bilateral combine ----
    float num = 0.f, den = 0.f;
    if (lt < 32) {
        if (lt < 27) {
            const int dz = lt / 9, dy = (lt / 3) % 3, dx = lt % 3;
            float acc = b2[0];
#pragma unroll
            for (int u = 0; u < 3; ++u)
#pragma unroll
                for (int v = 0; v < 3; ++v)
#pragma unroll
                    for (int q = 0; q < 3; ++q)
                        acc = fmaf(s_c1[grp][(dz + u) * 25 + (dy + v) * 5 + (dx + q)],
                                   w2[u * 9 + v * 3 + q], acc);
            const float r = fmaxf(acc, 0.f);
            const float wgt = fmaf(dom[lt], r, 1e-10f);

            // x patch value with H/W zero padding
            const int dd  = n / 9216;
            const int rem = n - dd * 9216;
            const int h   = rem / 96;
            const int w   = rem - h * 96;
            const int yy = h - 1 + dy;
            const int xx = w - 1 + dx;
            float xv = 0.f;
            if (yy >= 0 && yy < 96 && xx >= 0 && xx < 96)
                xv = x[(dd + 1 + dz) * 9216 + yy * 96 + xx];
            num = wgt * xv;
            den = wgt;
        }
        // reduce over lanes 0..31 of the group's first wave (27..31 carry zeros)
#pragma unroll
        for (int off = 16; off > 0; off >>= 1) {
            num += __shfl_down(num, off, 32);
            den += __shfl_down(den, off, 32);
        }
        if (lt == 0) out[n] = num / den;
    }
}

extern "C" void kernel_launch(void* const* d_in, const int* in_sizes, int n_in,
                              void* d_out, int out_size, void* d_ws, size_t ws_size,
                              hipStream_t stream) {
    const float* x     = (const float*)d_in[0];
    const float* dn    = (const float*)d_in[1];
    const float* guide = (const float*)d_in[2];
    const float* w1_d  = (const float*)d_in[3];
    const float* b1_d  = (const float*)d_in[4];
    const float* w2_d  = (const float*)d_in[5];
    const float* b2_d  = (const float*)d_in[6];
    const float* w1_r  = (const float*)d_in[7];
    const float* b1_r  = (const float*)d_in[8];
    const float* w2_r  = (const float*)d_in[9];
    const float* b2_r  = (const float*)d_in[10];
    float* out = (float*)d_out;
    float* dom = (float*)d_ws;   // 27 floats of scratch

    domain_branch_kernel<<<1, 128, 0, stream>>>(dn, w1_d, b1_d, w2_d, b2_d, dom);
    jbf_main_kernel<<<NPATCH / 2, 256, 0, stream>>>(guide, x, w1_r, b1_r, w2_r,
                                                    b2_r, dom, out);
}

// Round 2
// 80.136 us; speedup vs baseline: 1.3608x; 1.3608x over previous
//
#include <hip/hip_runtime.h>
#include <hip/hip_fp16.h>

// Joint bilateral filter block — thread-per-patch redesign.
// x (1,1,20,96,96) f32; guide_im (N,343) f32, N = 16*96*96 = 147456;
// out n = dd*9216 + h*96 + w uses x depths dd+1..dd+3, H/W zero-pad.

#define NPATCH 147456
#define NBLK   2304        // 64 patches per block, exact
#define SLICE_H 50         // halves per z-slice in LDS (49 data + 1 pad)
#define PATCH_H 350        // 7 slices
#define PATCH_D 175        // dwords per patch (mod 32 = 15, coprime -> conflict-free)

// ---------------- Kernel A: domain branch (runs once, 1 block) --------------
__global__ __launch_bounds__(128) void domain_branch_kernel(
    const float* __restrict__ dn,
    const float* __restrict__ w1, const float* __restrict__ b1,
    const float* __restrict__ w2, const float* __restrict__ b2,
    float* __restrict__ dom_out)
{
    __shared__ float s_in[344];
    __shared__ float s_c1[128];
    const int t = threadIdx.x;
    for (int idx = t; idx < 343; idx += 128) s_in[idx] = dn[idx];
    __syncthreads();
    if (t < 125) {
        const int i = t / 25, j = (t / 5) % 5, k = t % 5;
        float acc = b1[0];
        const float* base = &s_in[i * 49 + j * 7 + k];
#pragma unroll
        for (int dz = 0; dz < 3; ++dz)
#pragma unroll
            for (int dy = 0; dy < 3; ++dy)
#pragma unroll
                for (int dx = 0; dx < 3; ++dx)
                    acc = fmaf(base[dz * 49 + dy * 7 + dx], w1[dz * 9 + dy * 3 + dx], acc);
        s_c1[t] = fmaxf(acc, 0.f);
    }
    __syncthreads();
    if (t < 27) {
        const int dz = t / 9, dy = (t / 3) % 3, dx = t % 3;
        float acc = b2[0];
#pragma unroll
        for (int u = 0; u < 3; ++u)
#pragma unroll
            for (int v = 0; v < 3; ++v)
#pragma unroll
                for (int q = 0; q < 3; ++q)
                    acc = fmaf(s_c1[(dz + u) * 25 + (dy + v) * 5 + (dx + q)],
                               w2[u * 9 + v * 3 + q], acc);
        dom_out[t] = fmaxf(acc, 0.f);
    }
}

// ---------------- helpers ----------------
__device__ __forceinline__ float h2f_lo(unsigned int q) {
    return __half2float(__ushort_as_half((unsigned short)(q & 0xffffu)));
}
__device__ __forceinline__ float h2f_hi(unsigned int q) {
    return __half2float(__ushort_as_half((unsigned short)(q >> 16)));
}

// Load row (u, y) of the 7x7x7 fp16 patch (slice-padded layout) into d[0..6].
// u, y must be compile-time constants after unrolling -> all offsets fold.
__device__ __forceinline__ void load_row(const unsigned int* __restrict__ S, float* d,
                                         int u, int y) {
    const int h0  = u * SLICE_H + y * 7;   // half offset within slab base
    const int par = y & 1;                 // h0 parity (SLICE_H even)
    const int d0  = (h0 - par) >> 1;
    unsigned int q0 = S[d0], q1 = S[d0 + 1], q2 = S[d0 + 2], q3 = S[d0 + 3];
    if (par == 0) {
        d[0] = h2f_lo(q0); d[1] = h2f_hi(q0); d[2] = h2f_lo(q1); d[3] = h2f_hi(q1);
        d[4] = h2f_lo(q2); d[5] = h2f_hi(q2); d[6] = h2f_lo(q3);
    } else {
        d[0] = h2f_hi(q0); d[1] = h2f_lo(q1); d[2] = h2f_hi(q1); d[3] = h2f_lo(q2);
        d[4] = h2f_hi(q2); d[5] = h2f_lo(q3); d[6] = h2f_hi(q3);
    }
}

// ---------------- Kernel B: range branch + bilateral combine ----------------
__global__ __launch_bounds__(64) void jbf_main_kernel(
    const float* __restrict__ guide, const float* __restrict__ x,
    const float* __restrict__ w1, const float* __restrict__ b1,
    const float* __restrict__ w2, const float* __restrict__ b2,
    const float* __restrict__ dom, float* __restrict__ out)
{
    __shared__ unsigned short lds[64 * PATCH_H];   // 44,800 B -> 3 blocks/CU

    const int l   = threadIdx.x;
    const int blk = blockIdx.x;

    // ============== stage 64 patches (21952 f32, contiguous) -> fp16 LDS ===
    const float4* __restrict__ src =
        reinterpret_cast<const float4*>(guide + (size_t)blk * (64 * 343));

    // per-lane incremental (position-in-slice rs, LDS half index dst)
    {
        int flat = l * 4;                 // 0..252, always patch 0 of this tile
        int dz0  = flat / 49;
        int rs   = flat - dz0 * 49;
        int dst  = dz0 * SLICE_H + rs;

#define STORE_ELT(v) do {                                        \
            lds[dst] = __half_as_ushort(__float2half(v));        \
            ++dst; ++rs; if (rs == 49) { rs = 0; ++dst; }        \
        } while (0)

#define PROCESS4(c) do {                                         \
            STORE_ELT((c).x); STORE_ELT((c).y);                  \
            STORE_ELT((c).z); STORE_ELT((c).w);                  \
            int rs2 = rs + 252; int wr = (rs2 >= 294) ? 6 : 5;   \
            rs = rs2 - wr * 49; dst += 252 + wr;                 \
        } while (0)

        float4 buf[4];
#pragma unroll
        for (int k = 0; k < 4; ++k) buf[k] = src[k * 64 + l];

#pragma unroll 1
        for (int it0 = 0; it0 < 84; it0 += 4) {
#pragma unroll
            for (int k = 0; k < 4; ++k) {
                float4 cur = buf[k];
                int idx = (it0 + 4 + k) * 64 + l;
                if (idx > 5487) idx = 5487;      // clamp (safe dup load)
                buf[k] = src[idx];
                PROCESS4(cur);                   // iters 0..83: all elements valid
            }
        }
        PROCESS4(buf[0]);                        // iter 84: all valid
        if (l < 48) PROCESS4(buf[1]);            // iter 85: flats 21760+4l+j < 21952
#undef STORE_ELT
#undef PROCESS4
    }
    __syncthreads();

    // ===================== per-thread conv1+conv2 (fused) ===================
    const unsigned int* __restrict__ P =
        reinterpret_cast<const unsigned int*>(lds) + l * PATCH_D;

    const float bb1 = b1[0];
    float a2[3][3][3];
#pragma unroll
    for (int a = 0; a < 3; ++a)
#pragma unroll
        for (int b = 0; b < 3; ++b)
#pragma unroll
            for (int c = 0; c < 3; ++c) a2[a][b][c] = b2[0];

#pragma unroll 1
    for (int i = 0; i < 5; ++i) {                 // c1 z-slab
        const unsigned int* S = P + i * 25;       // +i*50 halves
        float rw[3][3][7];                        // [u][y%3][k]
#pragma unroll
        for (int j = 0; j < 5; ++j) {
            if (j == 0) {
#pragma unroll
                for (int u = 0; u < 3; ++u)
#pragma unroll
                    for (int y = 0; y < 3; ++y) load_row(S, rw[u][y], u, y);
            } else {
                const int y = j + 2;
#pragma unroll
                for (int u = 0; u < 3; ++u) load_row(S, rw[u][y % 3], u, y);
            }

            // c1 row (i, j, k=0..4)
            float c1r[5];
#pragma unroll
            for (int k = 0; k < 5; ++k) {
                float a = bb1;
#pragma unroll
                for (int u = 0; u < 3; ++u)
#pragma unroll
                    for (int v = 0; v < 3; ++v) {
                        const float* rr = rw[u][(j + v) % 3];
#pragma unroll
                        for (int w = 0; w < 3; ++w)
                            a = fmaf(rr[k + w], w1[u * 9 + v * 3 + w], a);
                    }
                c1r[k] = fmaxf(a, 0.f);
            }

            // fused conv2 accumulation
#pragma unroll
            for (int dz2 = 0; dz2 < 3; ++dz2) {
                const int u2 = i - dz2;
                if (u2 >= 0 && u2 < 3) {          // uniform runtime branch
#pragma unroll
                    for (int v2 = 0; v2 < 3; ++v2) {
                        const int dy2 = j - v2;   // compile-time check
                        if (dy2 >= 0 && dy2 < 3) {
#pragma unroll
                            for (int dx2 = 0; dx2 < 3; ++dx2)
#pragma unroll
                                for (int q = 0; q < 3; ++q)
                                    a2[dz2][dy2][dx2] =
                                        fmaf(c1r[dx2 + q],
                                             w2[u2 * 9 + v2 * 3 + q],
                                             a2[dz2][dy2][dx2]);
                        }
                    }
                }
            }
        }
    }

    // ===================== bilateral combine =====================
    const int n   = blk * 64 + l;
    const int dd  = n / 9216;
    const int rem = n - dd * 9216;
    const int h   = rem / 96;
    const int w_  = rem - h * 96;

    float num = 0.f, den = 0.f;
#pragma unroll
    for (int dz = 0; dz < 3; ++dz)
#pragma unroll
        for (int dy = 0; dy < 3; ++dy)
#pragma unroll
            for (int dx = 0; dx < 3; ++dx) {
                const float r2 = fmaxf(a2[dz][dy][dx], 0.f);
                const float wt = fmaf(dom[dz * 9 + dy * 3 + dx], r2, 1e-10f);
                const int yy = h - 1 + dy, xx = w_ - 1 + dx;
                float xv = 0.f;
                if (yy >= 0 && yy < 96 && xx >= 0 && xx < 96)
                    xv = x[(dd + 1 + dz) * 9216 + yy * 96 + xx];
                num = fmaf(wt, xv, num);
                den += wt;
            }
    out[n] = num / den;
}

extern "C" void kernel_launch(void* const* d_in, const int* in_sizes, int n_in,
                              void* d_out, int out_size, void* d_ws, size_t ws_size,
                              hipStream_t stream) {
    const float* x     = (const float*)d_in[0];
    const float* dn    = (const float*)d_in[1];
    const float* guide = (const float*)d_in[2];
    const float* w1_d  = (const float*)d_in[3];
    const float* b1_d  = (const float*)d_in[4];
    const float* w2_d  = (const float*)d_in[5];
    const float* b2_d  = (const float*)d_in[6];
    const float* w1_r  = (const float*)d_in[7];
    const float* b1_r  = (const float*)d_in[8];
    const float* w2_r  = (const float*)d_in[9];
    const float* b2_r  = (const float*)d_in[10];
    float* out = (float*)d_out;
    float* dom = (float*)d_ws;   // 27 floats of scratch

    domain_branch_kernel<<<1, 128, 0, stream>>>(dn, w1_d, b1_d, w2_d, b2_d, dom);
    jbf_main_kernel<<<NBLK, 64, 0, stream>>>(guide, x, w1_r, b1_r, w2_r,
                                             b2_r, dom, out);
}

// Round 3
// 63.059 us; speedup vs baseline: 1.7293x; 1.2708x over previous
//
#include <hip/hip_runtime.h>
#include <hip/hip_fp16.h>

// Joint bilateral filter block — 2-wave cooperative, thread-per-patch.
// x (1,1,20,96,96) f32; guide_im (N,343) f32, N = 16*96*96 = 147456;
// out n = dd*9216 + h*96 + w uses x depths dd+1..dd+3, H/W zero-pad.

#define NPATCH 147456
#define TPB     128        // 2 waves
#define PPB      64        // patches per block (one per lane, both waves share)
#define NBLK   (NPATCH / PPB)   // 2304
#define SLICE_H  50        // halves per z-slice in LDS (49 data + 1 pad)
#define PATCH_H 350        // 7 slices
#define PATCH_D 175        // dwords per patch (mod 32 = 15 -> conflict-free)
#define NF4    5488        // float4s per 64-patch tile (64*343/4)

// ---------------- Kernel A: domain branch (runs once, 1 block) --------------
__global__ __launch_bounds__(128) void domain_branch_kernel(
    const float* __restrict__ dn,
    const float* __restrict__ w1, const float* __restrict__ b1,
    const float* __restrict__ w2, const float* __restrict__ b2,
    float* __restrict__ dom_out)
{
    __shared__ float s_in[344];
    __shared__ float s_c1[128];
    const int t = threadIdx.x;
    for (int idx = t; idx < 343; idx += 128) s_in[idx] = dn[idx];
    __syncthreads();
    if (t < 125) {
        const int i = t / 25, j = (t / 5) % 5, k = t % 5;
        float acc = b1[0];
        const float* base = &s_in[i * 49 + j * 7 + k];
#pragma unroll
        for (int dz = 0; dz < 3; ++dz)
#pragma unroll
            for (int dy = 0; dy < 3; ++dy)
#pragma unroll
                for (int dx = 0; dx < 3; ++dx)
                    acc = fmaf(base[dz * 49 + dy * 7 + dx], w1[dz * 9 + dy * 3 + dx], acc);
        s_c1[t] = fmaxf(acc, 0.f);
    }
    __syncthreads();
    if (t < 27) {
        const int dz = t / 9, dy = (t / 3) % 3, dx = t % 3;
        float acc = b2[0];
#pragma unroll
        for (int u = 0; u < 3; ++u)
#pragma unroll
            for (int v = 0; v < 3; ++v)
#pragma unroll
                for (int q = 0; q < 3; ++q)
                    acc = fmaf(s_c1[(dz + u) * 25 + (dy + v) * 5 + (dx + q)],
                               w2[u * 9 + v * 3 + q], acc);
        dom_out[t] = fmaxf(acc, 0.f);
    }
}

// ---------------- helpers ----------------
__device__ __forceinline__ float h2f_lo(unsigned int q) {
    return __half2float(__ushort_as_half((unsigned short)(q & 0xffffu)));
}
__device__ __forceinline__ float h2f_hi(unsigned int q) {
    return __half2float(__ushort_as_half((unsigned short)(q >> 16)));
}

// Load row (u, y) of the 7x7x7 fp16 patch (slice-padded layout) into d[0..6].
// u, y must fold to compile-time constants after unrolling.
__device__ __forceinline__ void load_row(const unsigned int* __restrict__ S, float* d,
                                         int u, int y) {
    const int h0  = u * SLICE_H + y * 7;   // half offset within slab base
    const int par = y & 1;                 // h0 parity (SLICE_H even)
    const int d0  = (h0 - par) >> 1;
    unsigned int q0 = S[d0], q1 = S[d0 + 1], q2 = S[d0 + 2], q3 = S[d0 + 3];
    if (par == 0) {
        d[0] = h2f_lo(q0); d[1] = h2f_hi(q0); d[2] = h2f_lo(q1); d[3] = h2f_hi(q1);
        d[4] = h2f_lo(q2); d[5] = h2f_hi(q2); d[6] = h2f_lo(q3);
    } else {
        d[0] = h2f_hi(q0); d[1] = h2f_lo(q1); d[2] = h2f_hi(q1); d[3] = h2f_lo(q2);
        d[4] = h2f_hi(q2); d[5] = h2f_lo(q3); d[6] = h2f_hi(q3);
    }
}

// Run conv1+fused-conv2 row-tasks (i,j) from (IB,JB) to (IE,JE) inclusive,
// in row-major task order, accumulating into a2 (partial).
template<int IB, int JB, int IE, int JE>
__device__ __forceinline__ void run_tasks(const unsigned int* __restrict__ P,
                                          const float* __restrict__ w1, float bb1,
                                          const float* __restrict__ w2,
                                          float (&a2)[3][3][3])
{
#pragma unroll
    for (int i = IB; i <= IE; ++i) {              // c1 z-slab
        const unsigned int* S = P + i * 25;       // +i*50 halves
        float rw[3][3][7];                        // [u][y%3][k]
        const int j0 = (i == IB) ? JB : 0;
        const int j1 = (i == IE) ? JE : 4;
#pragma unroll
        for (int j = j0; j <= j1; ++j) {
            if (j == j0) {
#pragma unroll
                for (int u = 0; u < 3; ++u)
#pragma unroll
                    for (int dy = 0; dy < 3; ++dy)
                        load_row(S, rw[u][(j + dy) % 3], u, j + dy);
            } else {
#pragma unroll
                for (int u = 0; u < 3; ++u) load_row(S, rw[u][(j + 2) % 3], u, j + 2);
            }

            // c1 row (i, j, k=0..4)
            float c1r[5];
#pragma unroll
            for (int k = 0; k < 5; ++k) {
                float a = bb1;
#pragma unroll
                for (int u = 0; u < 3; ++u)
#pragma unroll
                    for (int v = 0; v < 3; ++v) {
                        const float* rr = rw[u][(j + v) % 3];
#pragma unroll
                        for (int w = 0; w < 3; ++w)
                            a = fmaf(rr[k + w], w1[u * 9 + v * 3 + w], a);
                    }
                c1r[k] = fmaxf(a, 0.f);
            }

            // fused conv2 accumulation
#pragma unroll
            for (int dz2 = 0; dz2 < 3; ++dz2) {
                const int u2 = i - dz2;
                if (u2 >= 0 && u2 < 3) {
#pragma unroll
                    for (int v2 = 0; v2 < 3; ++v2) {
                        const int dy2 = j - v2;
                        if (dy2 >= 0 && dy2 < 3) {
#pragma unroll
                            for (int dx2 = 0; dx2 < 3; ++dx2)
#pragma unroll
                                for (int q = 0; q < 3; ++q)
                                    a2[dz2][dy2][dx2] =
                                        fmaf(c1r[dx2 + q],
                                             w2[u2 * 9 + v2 * 3 + q],
                                             a2[dz2][dy2][dx2]);
                        }
                    }
                }
            }
        }
    }
}

// ---------------- Kernel B: range branch + bilateral combine ----------------
__global__ __launch_bounds__(TPB) void jbf_main_kernel(
    const float* __restrict__ guide, const float* __restrict__ x,
    const float* __restrict__ w1, const float* __restrict__ b1,
    const float* __restrict__ w2, const float* __restrict__ b2,
    const float* __restrict__ dom, float* __restrict__ out)
{
    __shared__ unsigned short lds[PPB * PATCH_H];   // 44,800 B
    __shared__ float part[PPB][27];                 //  6,912 B  (total 51.7 KB)

    const int tid  = threadIdx.x;
    const int wid  = tid >> 6;      // wave 0 / 1
    const int lane = tid & 63;      // patch owned by this thread
    const int blk  = blockIdx.x;

    // ============== stage 64 patches (21952 f32, contiguous) -> fp16 LDS ===
    const float4* __restrict__ src =
        reinterpret_cast<const float4*>(guide + (size_t)blk * (PPB * 343));
    {
        int flat   = tid * 4;                 // 0..508 (may cross patch 0/1)
        int patch  = flat / 343;
        int within = flat - patch * 343;
        int dz0    = within / 49;
        int rs     = within - dz0 * 49;
        int dst    = patch * PATCH_H + dz0 * SLICE_H + rs;

#define STORE_ELT(v) do {                                        \
            lds[dst] = __half_as_ushort(__float2half(v));        \
            ++dst; ++rs; if (rs == 49) { rs = 0; ++dst; }        \
        } while (0)

#define PROCESS4(c) do {                                         \
            STORE_ELT((c).x); STORE_ELT((c).y);                  \
            STORE_ELT((c).z); STORE_ELT((c).w);                  \
            int rs2 = rs + 508; int wr = (rs2 >= 539) ? 11 : 10; \
            rs = rs2 - wr * 49; dst += 508 + wr;                 \
        } while (0)

        float4 buf[4];
#pragma unroll
        for (int k = 0; k < 4; ++k) buf[k] = src[k * TPB + tid];

#pragma unroll 1
        for (int it0 = 0; it0 < 40; it0 += 4) {     // processes iters 0..39
#pragma unroll
            for (int k = 0; k < 4; ++k) {
                float4 cur = buf[k];
                int idx = (it0 + 4 + k) * TPB + tid;
                if (idx > NF4 - 1) idx = NF4 - 1;   // clamp (safe dup load)
                buf[k] = src[idx];
                PROCESS4(cur);
            }
        }
        PROCESS4(buf[0]);                 // iter 40 (valid all lanes)
        PROCESS4(buf[1]);                 // iter 41 (valid all lanes)
        if (tid < 112) PROCESS4(buf[2]);  // iter 42 partial: 5376+tid < 5488
#undef STORE_ELT
#undef PROCESS4
    }
    __syncthreads();

    // ===================== per-thread conv1+conv2 (task-split) ==============
    const unsigned int* __restrict__ P =
        reinterpret_cast<const unsigned int*>(lds) + lane * PATCH_D;
    const float bb1 = b1[0];

    float a2[3][3][3];
    {
        const float init = (wid == 0) ? b2[0] : 0.f;   // bias added exactly once
#pragma unroll
        for (int a = 0; a < 3; ++a)
#pragma unroll
            for (int b = 0; b < 3; ++b)
#pragma unroll
                for (int c = 0; c < 3; ++c) a2[a][b][c] = init;
    }

    if (wid == 0) {
        run_tasks<0, 0, 2, 2>(P, w1, bb1, w2, a2);     // tasks (0,0)..(2,2): 13
    } else {
        run_tasks<2, 3, 4, 4>(P, w1, bb1, w2, a2);     // tasks (2,3)..(4,4): 12
#pragma unroll
        for (int t = 0; t < 27; ++t)
            part[lane][t] = a2[t / 9][(t / 3) % 3][t % 3];
    }
    __syncthreads();

    // ===================== combine + bilateral (wave 0 only) ================
    if (wid == 0) {
        const int n   = blk * PPB + lane;
        const int dd  = n / 9216;
        const int rem = n - dd * 9216;
        const int h   = rem / 96;
        const int w_  = rem - h * 96;

        float num = 0.f, den = 0.f;
#pragma unroll
        for (int dz = 0; dz < 3; ++dz)
#pragma unroll
            for (int dy = 0; dy < 3; ++dy)
#pragma unroll
                for (int dx = 0; dx < 3; ++dx) {
                    const int t = dz * 9 + dy * 3 + dx;
                    const float r2 = fmaxf(a2[dz][dy][dx] + part[lane][t], 0.f);
                    const float wt = fmaf(dom[t], r2, 1e-10f);
                    const int yy = h - 1 + dy, xx = w_ - 1 + dx;
                    float xv = 0.f;
                    if (yy >= 0 && yy < 96 && xx >= 0 && xx < 96)
                        xv = x[(dd + 1 + dz) * 9216 + yy * 96 + xx];
                    num = fmaf(wt, xv, num);
                    den += wt;
                }
        out[n] = num / den;
    }
}

extern "C" void kernel_launch(void* const* d_in, const int* in_sizes, int n_in,
                              void* d_out, int out_size, void* d_ws, size_t ws_size,
                              hipStream_t stream) {
    const float* x     = (const float*)d_in[0];
    const float* dn    = (const float*)d_in[1];
    const float* guide = (const float*)d_in[2];
    const float* w1_d  = (const float*)d_in[3];
    const float* b1_d  = (const float*)d_in[4];
    const float* w2_d  = (const float*)d_in[5];
    const float* b2_d  = (const float*)d_in[6];
    const float* w1_r  = (const float*)d_in[7];
    const float* b1_r  = (const float*)d_in[8];
    const float* w2_r  = (const float*)d_in[9];
    const float* b2_r  = (const float*)d_in[10];
    float* out = (float*)d_out;
    float* dom = (float*)d_ws;   // 27 floats of scratch

    domain_branch_kernel<<<1, 128, 0, stream>>>(dn, w1_d, b1_d, w2_d, b2_d, dom);
    jbf_main_kernel<<<NBLK, TPB, 0, stream>>>(guide, x, w1_r, b1_r, w2_r,
                                              b2_r, dom, out);
}

// Round 4
// 52.538 us; speedup vs baseline: 2.0756x; 1.2002x over previous
//
#include <hip/hip_runtime.h>
#include <hip/hip_fp16.h>

// Joint bilateral filter block — 4-wave cooperative, thread-per-patch.
// x (1,1,20,96,96) f32; guide_im (N,343) f32, N = 16*96*96 = 147456;
// out n = dd*9216 + h*96 + w uses x depths dd+1..dd+3, H/W zero-pad.

#define NPATCH 147456
#define TPB     256        // 4 waves
#define PPB      64        // patches per block (one per lane, all waves share)
#define NBLK   (NPATCH / PPB)   // 2304
#define PATCH_H 346        // halves per patch: 343 data + 3 pad
#define PATCH_D 173        // dwords per patch (odd -> conflict-free lane reads)
#define NF4    5488        // float4s per 64-patch tile (64*343/4)

// ---------------- Kernel A: domain branch (runs once, 1 block) --------------
__global__ __launch_bounds__(128) void domain_branch_kernel(
    const float* __restrict__ dn,
    const float* __restrict__ w1, const float* __restrict__ b1,
    const float* __restrict__ w2, const float* __restrict__ b2,
    float* __restrict__ dom_out)
{
    __shared__ float s_in[344];
    __shared__ float s_c1[128];
    const int t = threadIdx.x;
    for (int idx = t; idx < 343; idx += 128) s_in[idx] = dn[idx];
    __syncthreads();
    if (t < 125) {
        const int i = t / 25, j = (t / 5) % 5, k = t % 5;
        float acc = b1[0];
        const float* base = &s_in[i * 49 + j * 7 + k];
#pragma unroll
        for (int dz = 0; dz < 3; ++dz)
#pragma unroll
            for (int dy = 0; dy < 3; ++dy)
#pragma unroll
                for (int dx = 0; dx < 3; ++dx)
                    acc = fmaf(base[dz * 49 + dy * 7 + dx], w1[dz * 9 + dy * 3 + dx], acc);
        s_c1[t] = fmaxf(acc, 0.f);
    }
    __syncthreads();
    if (t < 27) {
        const int dz = t / 9, dy = (t / 3) % 3, dx = t % 3;
        float acc = b2[0];
#pragma unroll
        for (int u = 0; u < 3; ++u)
#pragma unroll
            for (int v = 0; v < 3; ++v)
#pragma unroll
                for (int q = 0; q < 3; ++q)
                    acc = fmaf(s_c1[(dz + u) * 25 + (dy + v) * 5 + (dx + q)],
                               w2[u * 9 + v * 3 + q], acc);
        dom_out[t] = fmaxf(acc, 0.f);
    }
}

// ---------------- helpers ----------------
__device__ __forceinline__ float h2f_lo(unsigned int q) {
    return __half2float(__ushort_as_half((unsigned short)(q & 0xffffu)));
}
__device__ __forceinline__ float h2f_hi(unsigned int q) {
    return __half2float(__ushort_as_half((unsigned short)(q >> 16)));
}

// Load row y of absolute z-slice zi of the 7x7x7 fp16 patch (linear 343+3pad
// layout) into d[0..6]. zi, y fold to compile-time constants after unrolling.
__device__ __forceinline__ void load_row(const unsigned int* __restrict__ P, float* d,
                                         int zi, int y) {
    const int h0  = zi * 49 + y * 7;       // half offset within patch
    const int par = h0 & 1;                // compile-time
    const int d0  = (h0 - par) >> 1;
    unsigned int q0 = P[d0], q1 = P[d0 + 1], q2 = P[d0 + 2], q3 = P[d0 + 3];
    if (par == 0) {
        d[0] = h2f_lo(q0); d[1] = h2f_hi(q0); d[2] = h2f_lo(q1); d[3] = h2f_hi(q1);
        d[4] = h2f_lo(q2); d[5] = h2f_hi(q2); d[6] = h2f_lo(q3);
    } else {
        d[0] = h2f_hi(q0); d[1] = h2f_lo(q1); d[2] = h2f_hi(q1); d[3] = h2f_lo(q2);
        d[4] = h2f_hi(q2); d[5] = h2f_lo(q3); d[6] = h2f_hi(q3);
    }
}

// Run conv1+fused-conv2 row-tasks (i,j) from (IB,JB) to (IE,JE) inclusive,
// in row-major task order, accumulating into a2 (partial).
template<int IB, int JB, int IE, int JE>
__device__ __forceinline__ void run_tasks(const unsigned int* __restrict__ P,
                                          const float* __restrict__ w1, float bb1,
                                          const float* __restrict__ w2,
                                          float (&a2)[3][3][3])
{
#pragma unroll
    for (int i = IB; i <= IE; ++i) {              // c1 z-slab (input slices i..i+2)
        float rw[3][3][7];                        // [u][y%3][k]
        const int j0 = (i == IB) ? JB : 0;
        const int j1 = (i == IE) ? JE : 4;
#pragma unroll
        for (int j = j0; j <= j1; ++j) {
            if (j == j0) {
#pragma unroll
                for (int u = 0; u < 3; ++u)
#pragma unroll
                    for (int dy = 0; dy < 3; ++dy)
                        load_row(P, rw[u][(j + dy) % 3], i + u, j + dy);
            } else {
#pragma unroll
                for (int u = 0; u < 3; ++u)
                    load_row(P, rw[u][(j + 2) % 3], i + u, j + 2);
            }

            // c1 row (i, j, k=0..4)
            float c1r[5];
#pragma unroll
            for (int k = 0; k < 5; ++k) {
                float a = bb1;
#pragma unroll
                for (int u = 0; u < 3; ++u)
#pragma unroll
                    for (int v = 0; v < 3; ++v) {
                        const float* rr = rw[u][(j + v) % 3];
#pragma unroll
                        for (int w = 0; w < 3; ++w)
                            a = fmaf(rr[k + w], w1[u * 9 + v * 3 + w], a);
                    }
                c1r[k] = fmaxf(a, 0.f);
            }

            // fused conv2 accumulation
#pragma unroll
            for (int dz2 = 0; dz2 < 3; ++dz2) {
                const int u2 = i - dz2;
                if (u2 >= 0 && u2 < 3) {
#pragma unroll
                    for (int v2 = 0; v2 < 3; ++v2) {
                        const int dy2 = j - v2;
                        if (dy2 >= 0 && dy2 < 3) {
#pragma unroll
                            for (int dx2 = 0; dx2 < 3; ++dx2)
#pragma unroll
                                for (int q = 0; q < 3; ++q)
                                    a2[dz2][dy2][dx2] =
                                        fmaf(c1r[dx2 + q],
                                             w2[u2 * 9 + v2 * 3 + q],
                                             a2[dz2][dy2][dx2]);
                        }
                    }
                }
            }
        }
    }
}

// ---------------- Kernel B: range branch + bilateral combine ----------------
__global__ __launch_bounds__(TPB, 3) void jbf_main_kernel(
    const float* __restrict__ guide, const float* __restrict__ x,
    const float* __restrict__ w1, const float* __restrict__ b1,
    const float* __restrict__ w2, const float* __restrict__ b2,
    const float* __restrict__ dom, float* __restrict__ out)
{
    // partials buffer aliases the (dead-by-then) patch tile: 44,288 B total
    union SM {
        unsigned short tile[PPB * PATCH_H];   // 44,288 B
        float part[3][PPB][27];               // 20,736 B
    };
    __shared__ SM sm;

    const int tid  = threadIdx.x;
    const int wid  = tid >> 6;      // wave 0..3
    const int lane = tid & 63;      // patch owned by this thread
    const int blk  = blockIdx.x;

    // ============== stage 64 patches (21952 f32, contiguous) -> fp16 LDS ===
    const float4* __restrict__ src =
        reinterpret_cast<const float4*>(guide + (size_t)blk * (PPB * 343));

#define STORE4(IT, C) do {                                       \
        int flat = (IT) * (TPB * 4) + tid * 4;                   \
        int p    = flat / 343;                                   \
        int rs   = flat - p * 343;                               \
        int dst  = p * PATCH_H + rs;                             \
        float v4[4] = {(C).x, (C).y, (C).z, (C).w};              \
        _Pragma("unroll")                                        \
        for (int e = 0; e < 4; ++e) {                            \
            sm.tile[dst] = __half_as_ushort(__float2half(v4[e]));\
            ++dst; if (++rs == 343) { rs = 0; dst += 3; }        \
        }                                                        \
    } while (0)

    {
        float4 buf[4];
#pragma unroll
        for (int k = 0; k < 4; ++k) buf[k] = src[k * TPB + tid];

#pragma unroll 1
        for (int it0 = 0; it0 < 20; it0 += 4) {     // processes iters 0..19
#pragma unroll
            for (int k = 0; k < 4; ++k) {
                float4 cur = buf[k];
                int idx = (it0 + 4 + k) * TPB + tid;
                if (idx > NF4 - 1) idx = NF4 - 1;   // clamp (safe dup load)
                buf[k] = src[idx];
                STORE4(it0 + k, cur);
            }
        }
        STORE4(20, buf[0]);                  // iter 20: 5120+tid < 5488, all valid
        if (tid < 112) STORE4(21, buf[1]);   // iter 21 partial: 5376+tid < 5488
    }
#undef STORE4
    __syncthreads();

    // ===================== per-thread conv1+conv2 (4-way task split) ========
    const unsigned int* __restrict__ P =
        reinterpret_cast<const unsigned int*>(sm.tile) + lane * PATCH_D;
    const float bb1 = b1[0];

    float a2[3][3][3];
    {
        const float init = (wid == 0) ? b2[0] : 0.f;   // bias added exactly once
#pragma unroll
        for (int a = 0; a < 3; ++a)
#pragma unroll
            for (int b = 0; b < 3; ++b)
#pragma unroll
                for (int c = 0; c < 3; ++c) a2[a][b][c] = init;
    }

    if      (wid == 0) run_tasks<0, 0, 1, 1>(P, w1, bb1, w2, a2);  // 7 tasks
    else if (wid == 1) run_tasks<1, 2, 2, 3>(P, w1, bb1, w2, a2);  // 7 tasks
    else if (wid == 2) run_tasks<2, 4, 3, 4>(P, w1, bb1, w2, a2);  // 6 tasks
    else               run_tasks<4, 0, 4, 4>(P, w1, bb1, w2, a2);  // 5 tasks

    __syncthreads();     // all tile reads complete before aliasing as `part`

    if (wid != 0) {
#pragma unroll
        for (int t = 0; t < 27; ++t)
            sm.part[wid - 1][lane][t] = a2[t / 9][(t / 3) % 3][t % 3];
    }
    __syncthreads();

    // ===================== combine + bilateral (wave 0 only) ================
    if (wid == 0) {
        const int n   = blk * PPB + lane;
        const int dd  = n / 9216;
        const int rem = n - dd * 9216;
        const int h   = rem / 96;
        const int w_  = rem - h * 96;

        float num = 0.f, den = 0.f;
#pragma unroll
        for (int dz = 0; dz < 3; ++dz)
#pragma unroll
            for (int dy = 0; dy < 3; ++dy)
#pragma unroll
                for (int dx = 0; dx < 3; ++dx) {
                    const int t = dz * 9 + dy * 3 + dx;
                    const float r2 = fmaxf(a2[dz][dy][dx] + sm.part[0][lane][t]
                                           + sm.part[1][lane][t]
                                           + sm.part[2][lane][t], 0.f);
                    const float wt = fmaf(dom[t], r2, 1e-10f);
                    const int yy = h - 1 + dy, xx = w_ - 1 + dx;
                    float xv = 0.f;
                    if (yy >= 0 && yy < 96 && xx >= 0 && xx < 96)
                        xv = x[(dd + 1 + dz) * 9216 + yy * 96 + xx];
                    num = fmaf(wt, xv, num);
                    den += wt;
                }
        out[n] = num / den;
    }
}

extern "C" void kernel_launch(void* const* d_in, const int* in_sizes, int n_in,
                              void* d_out, int out_size, void* d_ws, size_t ws_size,
                              hipStream_t stream) {
    const float* x     = (const float*)d_in[0];
    const float* dn    = (const float*)d_in[1];
    const float* guide = (const float*)d_in[2];
    const float* w1_d  = (const float*)d_in[3];
    const float* b1_d  = (const float*)d_in[4];
    const float* w2_d  = (const float*)d_in[5];
    const float* b2_d  = (const float*)d_in[6];
    const float* w1_r  = (const float*)d_in[7];
    const float* b1_r  = (const float*)d_in[8];
    const float* w2_r  = (const float*)d_in[9];
    const float* b2_r  = (const float*)d_in[10];
    float* out = (float*)d_out;
    float* dom = (float*)d_ws;   // 27 floats of scratch

    domain_branch_kernel<<<1, 128, 0, stream>>>(dn, w1_d, b1_d, w2_d, b2_d, dom);
    jbf_main_kernel<<<NBLK, TPB, 0, stream>>>(guide, x, w1_r, b1_r, w2_r,
                                              b2_r, dom, out);
}